// Round 9
// baseline (17.011 us; speedup 1.0000x reference)
//
#include <hip/hip_runtime.h>
#include <hip/hip_fp16.h>
#include <math.h>

#define NG 2048
#define HH 128
#define WW 128
#define FOCAL 110.0f
#define NEARP 0.3f
#define EPSS 1e-4f
#define LOWPASS (0.3f / (110.0f * 110.0f))
#define L2E 1.4426950408889634f
#define INV_L2E 0.6931471805599453f
#define LN_INV_ACUT 11.512925465f      // ln(1e5): alpha cutoff 1e-5
#define TAU_MAX 23.02585093f           // 2*ln(1e5) >= tau for any opacity

#define NSEG 16

// fast native f32 ops (error ~1e-5 rel; threshold 1.6e-2, current absmax 3.9e-3)
#define EXP2F(x) __builtin_amdgcn_exp2f(x)
#define RCPF(x)  __builtin_amdgcn_rcpf(x)

__device__ __forceinline__ float fast_sigmoid(float x) {
    return RCPF(1.0f + EXP2F(-x * L2E));
}

// One block per 8x8 tile.
// Phase 0: cheap conservative cull, NO opacity/quat/cov math:
//          a <= smax^2*iz^2*(1+u^2)  (w2c rows orthonormal, exact)
//          tau <= TAU_MAX            (constant; tight within ~3-6% radius)
//          False positives are harmless: they get exact conic+osig in 1b and
//          contribute exactly the reference value.
// Phase 1b: full conic + osig + rgb for candidates only (~L of 2048).
// Phase 2: parallel rank sort by (z, idx) — 16 threads/item shfl-reduce.
// Phase 4: segmented composite via rank->slot indirection; ordered combine.
__global__ __launch_bounds__(1024) void splat_fused(const float* __restrict__ pos,
                                                    const float* __restrict__ rgb,
                                                    const float* __restrict__ opa,
                                                    const float4* __restrict__ quat,
                                                    const float* __restrict__ scale,
                                                    const float* __restrict__ w2c,
                                                    const float* __restrict__ tran,
                                                    float* __restrict__ out) {
    __shared__ unsigned long long zk[NG];   // candidate keys by slot            16 KB
    __shared__ float4 ppA[NG];              // ph0 {u,v,iz,-} -> {u,v,Af,Bf}     32 KB
    __shared__ float4 ppB[NG];              // {Cf,osig,h2(r,g),h2(b,0)}         32 KB
    __shared__ unsigned short srt[NG];      // rank -> slot                       4 KB
    __shared__ float4 seg[NSEG][64];        //                                    4 KB
    __shared__ int cnt;

    int t = threadIdx.x;
    int lane = t & 63;
    int wave = t >> 6;
    int bx = blockIdx.x & 15, by = blockIdx.x >> 4;

    float cu = ((float)(bx * 8) + 3.5f - 63.5f) / FOCAL;
    float cv = ((float)(by * 8) + 3.5f - 63.5f) / FOCAL;
    const float hw = 3.5f / FOCAL;

    if (t == 0) cnt = 0;
    __syncthreads();

    // uniform camera (scalar loads)
    float W00 = w2c[0], W01 = w2c[1], W02 = w2c[2];
    float W10 = w2c[3], W11 = w2c[4], W12 = w2c[5];
    float W20 = w2c[6], W21 = w2c[7], W22 = w2c[8];
    float t0 = tran[0], t1 = tran[1], t2 = tran[2];

    // ---- phase 0: cheap-bound cull (2 gaussians/thread), compact candidates ----
    #pragma unroll
    for (int part = 0; part < 2; ++part) {
        int g = t + part * 1024;

        float px = pos[g * 3 + 0], py = pos[g * 3 + 1], pz = pos[g * 3 + 2];
        float cx = W00 * px + W01 * py + W02 * pz + t0;
        float cy = W10 * px + W11 * py + W12 * pz + t1;
        float cz = W20 * px + W21 * py + W22 * pz + t2;

        bool valid = cz > NEARP;
        float iz = valid ? RCPF(cz) : 1.0f;
        float u = cx * iz;
        float v = cy * iz;

        float smax = fmaxf(fmaxf(fabsf(scale[g * 3 + 0]), fabsf(scale[g * 3 + 1])),
                           fabsf(scale[g * 3 + 2])) + EPSS;
        float s2iz2 = smax * smax * iz * iz * 1.0001f;
        float bound_a = fmaf(s2iz2, u * u, s2iz2) + LOWPASS;   // s2iz2*(1+u^2)+LP
        float bound_c = fmaf(s2iz2, v * v, s2iz2) + LOWPASS;

        float du = fmaxf(fabsf(u - cu) - hw, 0.0f);
        float dv = fmaxf(fabsf(v - cv) - hw, 0.0f);
        bool cand = valid &&
                    (du * du <= TAU_MAX * bound_a) && (dv * dv <= TAU_MAX * bound_c);

        if (cand) {
            int s = atomicAdd(&cnt, 1);
            zk[s] = ((unsigned long long)__float_as_uint(cz) << 32) | (unsigned int)g;
            ppA[s] = make_float4(u, v, iz, 0.0f);
        }
    }
    __syncthreads();
    int L = cnt;

    // ---- phase 1b: full conic + osig + rgb for candidates (masked pass) ----
    for (int i = t; i < L; i += 1024) {
        int g = (int)(zk[i] & 0xffffu);
        float4 cach = ppA[i];
        float u = cach.x, v = cach.y, iz = cach.z;

        float osig = fast_sigmoid(opa[g]);

        // K = J*W rows (2x3)
        float k00 = iz * (W00 - u * W20), k01 = iz * (W01 - u * W21), k02 = iz * (W02 - u * W22);
        float k10 = iz * (W10 - v * W20), k11 = iz * (W11 - v * W21), k12 = iz * (W12 - v * W22);

        float4 q = quat[g];
        float qw = q.x, qx = q.y, qy = q.z, qz = q.w;
        float qq = qw * qw + qx * qx + qy * qy + qz * qz;
        float inv = RCPF(__builtin_amdgcn_sqrtf(qq) + 1e-8f);
        qw *= inv; qx *= inv; qy *= inv; qz *= inv;
        float R00 = 1.0f - 2.0f * (qy * qy + qz * qz);
        float R01 = 2.0f * (qx * qy - qw * qz);
        float R02 = 2.0f * (qx * qz + qw * qy);
        float R10 = 2.0f * (qx * qy + qw * qz);
        float R11 = 1.0f - 2.0f * (qx * qx + qz * qz);
        float R12 = 2.0f * (qy * qz - qw * qx);
        float R20 = 2.0f * (qx * qz - qw * qy);
        float R21 = 2.0f * (qy * qz + qw * qx);
        float R22 = 1.0f - 2.0f * (qx * qx + qy * qy);

        float s0 = fabsf(scale[g * 3 + 0]) + EPSS;
        float s1 = fabsf(scale[g * 3 + 1]) + EPSS;
        float s2 = fabsf(scale[g * 3 + 2]) + EPSS;

        // G = K * R * diag(s)  (2x3); cov2 = G G^T
        float g00 = (k00 * R00 + k01 * R10 + k02 * R20) * s0;
        float g01 = (k00 * R01 + k01 * R11 + k02 * R21) * s1;
        float g02 = (k00 * R02 + k01 * R12 + k02 * R22) * s2;
        float g10 = (k10 * R00 + k11 * R10 + k12 * R20) * s0;
        float g11 = (k10 * R01 + k11 * R11 + k12 * R21) * s1;
        float g12 = (k10 * R02 + k11 * R12 + k12 * R22) * s2;

        float a = g00 * g00 + g01 * g01 + g02 * g02 + LOWPASS;
        float c = g10 * g10 + g11 * g11 + g12 * g12 + LOWPASS;
        float b = g00 * g10 + g01 * g11 + g02 * g12;

        float det = fmaxf(a * c - b * b, 1e-12f);
        float idet = RCPF(det);
        float Af = -0.5f * L2E * (c * idet);
        float Bf =  L2E * (b * idet);
        float Cf = -0.5f * L2E * (a * idet);

        float rr = fast_sigmoid(rgb[g * 3 + 0]);
        float gg = fast_sigmoid(rgb[g * 3 + 1]);
        float bb = fast_sigmoid(rgb[g * 3 + 2]);
        union { __half2 h; float f; } prg, pb;
        prg.h = __floats2half2_rn(rr, gg);
        pb.h  = __floats2half2_rn(bb, 0.0f);

        ppA[i] = make_float4(u, v, Af, Bf);
        ppB[i] = make_float4(Cf, osig, prg.f, pb.f);
    }

    // ---- phase 2: parallel rank sort (16 threads/item, shfl-reduce) ----
    {
        int sub = t & 15;
        for (int i = t >> 4; i < L; i += 64) {
            unsigned long long ki = zk[i];
            int r = 0;
            for (int j = sub; j < L; j += 16) r += (zk[j] < ki) ? 1 : 0;
            r += __shfl_xor(r, 1);
            r += __shfl_xor(r, 2);
            r += __shfl_xor(r, 4);
            r += __shfl_xor(r, 8);
            if (sub == 0) srt[r] = (unsigned short)i;
        }
    }
    __syncthreads();

    // ---- phase 4: segmented composite via rank->slot indirection ----
    int px = bx * 8 + (lane & 7);
    int py = by * 8 + (lane >> 3);
    float gu = ((float)px - 63.5f) / FOCAL;
    float gv = ((float)py - 63.5f) / FOCAL;

    int s = (L * wave) >> 4;
    int e = (L * (wave + 1)) >> 4;

    float T = 1.0f, cr = 0.0f, cg = 0.0f, cb = 0.0f;
    for (int i = s; i < e; ++i) {
        int slot = srt[i];               // wave-uniform broadcast read
        float4 q0 = ppA[slot];
        float4 q1 = ppB[slot];

        float dx = gu - q0.x;
        float dy = gv - q0.y;
        float t1v = fmaf(q0.w, dy, q0.z * dx);
        float p   = fmaf(t1v, dx, q1.x * (dy * dy));
        p = fminf(p, 0.0f);
        float gw = EXP2F(p);
        float alpha = fminf(q1.y * gw, 0.99f);
        float w = alpha * T;

        union { float f; __half2 h; } crg, cbb;
        crg.f = q1.z; cbb.f = q1.w;
        float2 rgv = __half22float2(crg.h);
        float bch = __low2float(cbb.h);

        cr = fmaf(w, rgv.x, cr);
        cg = fmaf(w, rgv.y, cg);
        cb = fmaf(w, bch, cb);
        T = fmaf(-alpha, T, T);
    }
    seg[wave][lane] = make_float4(cr, cg, cb, T);
    __syncthreads();

    // ordered combine of 16 segments -> output
    if (t < 64) {
        float Tt = 1.0f, r = 0.0f, g = 0.0f, b = 0.0f;
        #pragma unroll
        for (int sgi = 0; sgi < NSEG; ++sgi) {
            float4 v = seg[sgi][t];
            r = fmaf(Tt, v.x, r);
            g = fmaf(Tt, v.y, g);
            b = fmaf(Tt, v.z, b);
            Tt *= v.w;
        }
        int p = py * WW + px;
        out[p * 3 + 0] = r;
        out[p * 3 + 1] = g;
        out[p * 3 + 2] = b;
    }
}

extern "C" void kernel_launch(void* const* d_in, const int* in_sizes, int n_in,
                              void* d_out, int out_size, void* d_ws, size_t ws_size,
                              hipStream_t stream) {
    const float* pos   = (const float*)d_in[0];
    const float* rgb   = (const float*)d_in[1];
    const float* opa   = (const float*)d_in[2];
    const float4* quat = (const float4*)d_in[3];
    const float* scale = (const float*)d_in[4];
    const float* w2c   = (const float*)d_in[5];
    const float* tran  = (const float*)d_in[6];
    float* out = (float*)d_out;

    splat_fused<<<(HH * WW) / 64, 1024, 0, stream>>>(pos, rgb, opa, quat, scale, w2c, tran, out);
}

// Round 10
// 11.371 us; speedup vs baseline: 1.4960x; 1.4960x over previous
//
#include <hip/hip_runtime.h>
#include <hip/hip_fp16.h>
#include <math.h>

#define NG 2048
#define HH 128
#define WW 128
#define FOCAL 110.0f
#define NEARP 0.3f
#define EPSS 1e-4f
#define LOWPASS (0.3f / (110.0f * 110.0f))
#define L2E 1.4426950408889634f
#define INV_L2E 0.6931471805599453f
#define LN_INV_ACUT 11.512925465f   // ln(1e5): alpha cutoff 1e-5

#define NSEG 16

// fast native f32 ops (error ~1e-5 rel; threshold 1.6e-2, current absmax 3.9e-3)
#define EXP2F(x) __builtin_amdgcn_exp2f(x)
#define LOG2F(x) __builtin_amdgcn_logf(x)
#define RCPF(x)  __builtin_amdgcn_rcpf(x)

__device__ __forceinline__ float fast_sigmoid(float x) {
    return RCPF(1.0f + EXP2F(-x * L2E));
}

// One block per 8x8 tile.
// Phase 0: cheap exact-bound cull (no quat/cov math): a <= smax^2*iz^2*(1+u^2)
//          (w2c rows orthonormal -> |row0 of J*W|^2 = iz^2(1+u^2) exactly).
//          Candidates (~3x true survivors) compacted with (u,v,iz,osig) cached.
// Phase 1b: full conic + rgb only for candidates (masked pass, ~1/8 the volume).
// Phase 2: parallel rank sort by (z, idx).
// Phase 4: segmented composite via rank->slot indirection; ordered combine.
// False-positive candidates keep their true conic -> contribute exactly what
// the reference computes (pre-cull only drops alpha<1e-5 contributions).
__global__ __launch_bounds__(1024) void splat_fused(const float* __restrict__ pos,
                                                    const float* __restrict__ rgb,
                                                    const float* __restrict__ opa,
                                                    const float4* __restrict__ quat,
                                                    const float* __restrict__ scale,
                                                    const float* __restrict__ w2c,
                                                    const float* __restrict__ tran,
                                                    float* __restrict__ out) {
    __shared__ unsigned long long zk[NG];   // candidate keys by slot            16 KB
    __shared__ float4 ppA[NG];              // ph0: {u,v,iz,osig} -> {u,v,Af,Bf} 32 KB
    __shared__ float4 ppB[NG];              // {Cf,osig,h2(r,g),h2(b,0)}         32 KB
    __shared__ unsigned short srt[NG];      // rank -> slot                       4 KB
    __shared__ float4 seg[NSEG][64];        //                                    4 KB
    __shared__ int cnt;

    int t = threadIdx.x;
    int lane = t & 63;
    int wave = t >> 6;
    int bx = blockIdx.x & 15, by = blockIdx.x >> 4;

    float cu = ((float)(bx * 8) + 3.5f - 63.5f) / FOCAL;
    float cv = ((float)(by * 8) + 3.5f - 63.5f) / FOCAL;
    const float hw = 3.5f / FOCAL;

    if (t == 0) cnt = 0;
    __syncthreads();

    // uniform camera (scalar loads)
    float W00 = w2c[0], W01 = w2c[1], W02 = w2c[2];
    float W10 = w2c[3], W11 = w2c[4], W12 = w2c[5];
    float W20 = w2c[6], W21 = w2c[7], W22 = w2c[8];
    float t0 = tran[0], t1 = tran[1], t2 = tran[2];

    // ---- phase 0: cheap-bound cull (2 gaussians/thread), compact candidates ----
    #pragma unroll
    for (int part = 0; part < 2; ++part) {
        int g = t + part * 1024;

        float px = pos[g * 3 + 0], py = pos[g * 3 + 1], pz = pos[g * 3 + 2];
        float cx = W00 * px + W01 * py + W02 * pz + t0;
        float cy = W10 * px + W11 * py + W12 * pz + t1;
        float cz = W20 * px + W21 * py + W22 * pz + t2;

        bool valid = cz > NEARP;
        float iz = valid ? RCPF(cz) : 1.0f;
        float u = cx * iz;
        float v = cy * iz;

        // osig + tau = 2*(ln(osig)+ln(1e5));  ln(osig) = -log2(1+e)*ln2
        float e = EXP2F(-opa[g] * L2E);
        float osig = RCPF(1.0f + e);
        float tau = 2.0f * (LN_INV_ACUT - LOG2F(1.0f + e) * INV_L2E);

        float smax = fmaxf(fmaxf(fabsf(scale[g * 3 + 0]), fabsf(scale[g * 3 + 1])),
                           fabsf(scale[g * 3 + 2])) + EPSS;
        float s2iz2 = smax * smax * iz * iz * 1.0001f;
        float bound_a = fmaf(s2iz2, u * u, s2iz2) + LOWPASS;   // s2iz2*(1+u^2)+LP
        float bound_c = fmaf(s2iz2, v * v, s2iz2) + LOWPASS;

        float du = fmaxf(fabsf(u - cu) - hw, 0.0f);
        float dv = fmaxf(fabsf(v - cv) - hw, 0.0f);
        bool cand = valid && (tau > 0.0f) &&
                    (du * du <= tau * bound_a) && (dv * dv <= tau * bound_c);

        if (cand) {
            int s = atomicAdd(&cnt, 1);
            zk[s] = ((unsigned long long)__float_as_uint(cz) << 32) | (unsigned int)g;
            ppA[s] = make_float4(u, v, iz, osig);
        }
    }
    __syncthreads();
    int L = cnt;

    // ---- phase 1b: full conic + rgb for candidates (masked pass) ----
    for (int i = t; i < L; i += 1024) {
        int g = (int)(zk[i] & 0xffffu);
        float4 cach = ppA[i];
        float u = cach.x, v = cach.y, iz = cach.z, osig = cach.w;

        // K = J*W rows (2x3)
        float k00 = iz * (W00 - u * W20), k01 = iz * (W01 - u * W21), k02 = iz * (W02 - u * W22);
        float k10 = iz * (W10 - v * W20), k11 = iz * (W11 - v * W21), k12 = iz * (W12 - v * W22);

        float4 q = quat[g];
        float qw = q.x, qx = q.y, qy = q.z, qz = q.w;
        float qq = qw * qw + qx * qx + qy * qy + qz * qz;
        float inv = RCPF(__builtin_amdgcn_sqrtf(qq) + 1e-8f);
        qw *= inv; qx *= inv; qy *= inv; qz *= inv;
        float R00 = 1.0f - 2.0f * (qy * qy + qz * qz);
        float R01 = 2.0f * (qx * qy - qw * qz);
        float R02 = 2.0f * (qx * qz + qw * qy);
        float R10 = 2.0f * (qx * qy + qw * qz);
        float R11 = 1.0f - 2.0f * (qx * qx + qz * qz);
        float R12 = 2.0f * (qy * qz - qw * qx);
        float R20 = 2.0f * (qx * qz - qw * qy);
        float R21 = 2.0f * (qy * qz + qw * qx);
        float R22 = 1.0f - 2.0f * (qx * qx + qy * qy);

        float s0 = fabsf(scale[g * 3 + 0]) + EPSS;
        float s1 = fabsf(scale[g * 3 + 1]) + EPSS;
        float s2 = fabsf(scale[g * 3 + 2]) + EPSS;

        // G = K * R * diag(s)  (2x3); cov2 = G G^T
        float g00 = (k00 * R00 + k01 * R10 + k02 * R20) * s0;
        float g01 = (k00 * R01 + k01 * R11 + k02 * R21) * s1;
        float g02 = (k00 * R02 + k01 * R12 + k02 * R22) * s2;
        float g10 = (k10 * R00 + k11 * R10 + k12 * R20) * s0;
        float g11 = (k10 * R01 + k11 * R11 + k12 * R21) * s1;
        float g12 = (k10 * R02 + k11 * R12 + k12 * R22) * s2;

        float a = g00 * g00 + g01 * g01 + g02 * g02 + LOWPASS;
        float c = g10 * g10 + g11 * g11 + g12 * g12 + LOWPASS;
        float b = g00 * g10 + g01 * g11 + g02 * g12;

        float det = fmaxf(a * c - b * b, 1e-12f);
        float idet = RCPF(det);
        float Af = -0.5f * L2E * (c * idet);
        float Bf =  L2E * (b * idet);
        float Cf = -0.5f * L2E * (a * idet);

        float rr = fast_sigmoid(rgb[g * 3 + 0]);
        float gg = fast_sigmoid(rgb[g * 3 + 1]);
        float bb = fast_sigmoid(rgb[g * 3 + 2]);
        union { __half2 h; float f; } prg, pb;
        prg.h = __floats2half2_rn(rr, gg);
        pb.h  = __floats2half2_rn(bb, 0.0f);

        ppA[i] = make_float4(u, v, Af, Bf);
        ppB[i] = make_float4(Cf, osig, prg.f, pb.f);
    }

    // ---- phase 2: parallel rank sort (16 threads/item, shfl-reduce) ----
    {
        int sub = t & 15;
        for (int i = t >> 4; i < L; i += 64) {
            unsigned long long ki = zk[i];
            int r = 0;
            for (int j = sub; j < L; j += 16) r += (zk[j] < ki) ? 1 : 0;
            r += __shfl_xor(r, 1);
            r += __shfl_xor(r, 2);
            r += __shfl_xor(r, 4);
            r += __shfl_xor(r, 8);
            if (sub == 0) srt[r] = (unsigned short)i;
        }
    }
    __syncthreads();

    // ---- phase 4: segmented composite via rank->slot indirection ----
    int px = bx * 8 + (lane & 7);
    int py = by * 8 + (lane >> 3);
    float gu = ((float)px - 63.5f) / FOCAL;
    float gv = ((float)py - 63.5f) / FOCAL;

    int s = (L * wave) >> 4;
    int e = (L * (wave + 1)) >> 4;

    float T = 1.0f, cr = 0.0f, cg = 0.0f, cb = 0.0f;
    for (int i = s; i < e; ++i) {
        int slot = srt[i];               // wave-uniform broadcast read
        float4 q0 = ppA[slot];
        float4 q1 = ppB[slot];

        float dx = gu - q0.x;
        float dy = gv - q0.y;
        float t1v = fmaf(q0.w, dy, q0.z * dx);
        float p   = fmaf(t1v, dx, q1.x * (dy * dy));
        p = fminf(p, 0.0f);
        float gw = EXP2F(p);
        float alpha = fminf(q1.y * gw, 0.99f);
        float w = alpha * T;

        union { float f; __half2 h; } crg, cbb;
        crg.f = q1.z; cbb.f = q1.w;
        float2 rgv = __half22float2(crg.h);
        float bch = __low2float(cbb.h);

        cr = fmaf(w, rgv.x, cr);
        cg = fmaf(w, rgv.y, cg);
        cb = fmaf(w, bch, cb);
        T = fmaf(-alpha, T, T);
    }
    seg[wave][lane] = make_float4(cr, cg, cb, T);
    __syncthreads();

    // ordered combine of 16 segments -> output
    if (t < 64) {
        float Tt = 1.0f, r = 0.0f, g = 0.0f, b = 0.0f;
        #pragma unroll
        for (int sgi = 0; sgi < NSEG; ++sgi) {
            float4 v = seg[sgi][t];
            r = fmaf(Tt, v.x, r);
            g = fmaf(Tt, v.y, g);
            b = fmaf(Tt, v.z, b);
            Tt *= v.w;
        }
        int p = py * WW + px;
        out[p * 3 + 0] = r;
        out[p * 3 + 1] = g;
        out[p * 3 + 2] = b;
    }
}

extern "C" void kernel_launch(void* const* d_in, const int* in_sizes, int n_in,
                              void* d_out, int out_size, void* d_ws, size_t ws_size,
                              hipStream_t stream) {
    const float* pos   = (const float*)d_in[0];
    const float* rgb   = (const float*)d_in[1];
    const float* opa   = (const float*)d_in[2];
    const float4* quat = (const float4*)d_in[3];
    const float* scale = (const float*)d_in[4];
    const float* w2c   = (const float*)d_in[5];
    const float* tran  = (const float*)d_in[6];
    float* out = (float*)d_out;

    splat_fused<<<(HH * WW) / 64, 1024, 0, stream>>>(pos, rgb, opa, quat, scale, w2c, tran, out);
}